// Round 6
// baseline (990.772 us; speedup 1.0000x reference)
//
#include <hip/hip_runtime.h>
#include <hip/hip_bf16.h>
#include <math.h>

#define BB   8
#define DIMM 1024
#define TT   2048
#define CDD  128
#define KK   1024
#define QQ   8
#define MM   (BB*TT)     // 16384 tokens
#define NPAIR 28         // q*(q-1)/2 pairs p<q

typedef __attribute__((ext_vector_type(8))) short bf16x8;
typedef __attribute__((ext_vector_type(4))) float f32x4;

static __device__ __forceinline__ unsigned short f2bf(float f) {
    __hip_bfloat16 h = __float2bfloat16(f);
    unsigned short u; __builtin_memcpy(&u, &h, 2); return u;
}
static __device__ __forceinline__ float bf2f(unsigned short u) {
    __hip_bfloat16 h; __builtin_memcpy(&h, &u, 2); return __bfloat162float(h);
}

// ===========================================================================
// prep: emb [b][d][t] fp32 -> embT 3-way split bf16 [m=b*T+t][d]
__global__ __launch_bounds__(256) void prep_embT(
    const float* __restrict__ emb,
    unsigned short* __restrict__ Th, unsigned short* __restrict__ Tm,
    unsigned short* __restrict__ Tl)
{
    __shared__ float tile[32][36];
    const int t0 = blockIdx.x * 32, d0 = blockIdx.y * 32, b = blockIdx.z;
    const int tid = threadIdx.x;
    {
        int r = tid >> 3, cg = (tid & 7) << 2;
        *(float4*)&tile[r][cg] =
            *(const float4*)(emb + ((size_t)b * DIMM + d0 + r) * TT + t0 + cg);
    }
    __syncthreads();
    {
        int tt = tid >> 3, dg = (tid & 7) << 2;
        unsigned short h4[4], m4[4], l4[4];
        #pragma unroll
        for (int u = 0; u < 4; u++) {
            float v = tile[dg + u][tt];
            h4[u] = f2bf(v);              float v1 = bf2f(h4[u]);
            m4[u] = f2bf(v - v1);         float v2 = bf2f(m4[u]);
            l4[u] = f2bf(v - v1 - v2);
        }
        size_t o = ((size_t)b * TT + t0 + tt) * DIMM + d0 + dg;
        *(ushort4*)(Th + o) = *(ushort4*)h4;
        *(ushort4*)(Tm + o) = *(ushort4*)m4;
        *(ushort4*)(Tl + o) = *(ushort4*)l4;
    }
}

// prep: Wi [q][d][c] -> WiT 3-way split [q][c][d]
__global__ __launch_bounds__(256) void prep_wiT(
    const float* __restrict__ Wi,
    unsigned short* __restrict__ Th, unsigned short* __restrict__ Tm,
    unsigned short* __restrict__ Tl)
{
    __shared__ float tile[32][36];
    const int d0 = blockIdx.x * 32, c0 = blockIdx.y * 32, q = blockIdx.z;
    const int tid = threadIdx.x;
    {
        int r = tid >> 3, cg = (tid & 7) << 2;   // r: d, cg: c
        *(float4*)&tile[r][cg] =
            *(const float4*)(Wi + ((size_t)q * DIMM + d0 + r) * CDD + c0 + cg);
    }
    __syncthreads();
    {
        int cc = tid >> 3, dg = (tid & 7) << 2;
        unsigned short h4[4], m4[4], l4[4];
        #pragma unroll
        for (int u = 0; u < 4; u++) {
            float v = tile[dg + u][cc];
            h4[u] = f2bf(v);              float v1 = bf2f(h4[u]);
            m4[u] = f2bf(v - v1);         float v2 = bf2f(m4[u]);
            l4[u] = f2bf(v - v1 - v2);
        }
        size_t o = ((size_t)q * CDD + c0 + cc) * DIMM + d0 + dg;
        *(ushort4*)(Th + o) = *(ushort4*)h4;
        *(ushort4*)(Tm + o) = *(ushort4*)m4;
        *(ushort4*)(Tl + o) = *(ushort4*)l4;
    }
}

// prep: Wo [q][c][d] -> WoT hi/lo [q][d][c]
__global__ __launch_bounds__(256) void prep_woT(
    const float* __restrict__ Wo,
    unsigned short* __restrict__ Th, unsigned short* __restrict__ Tl)
{
    __shared__ float tile[32][36];
    const int c0 = blockIdx.x * 32, d0 = blockIdx.y * 32, q = blockIdx.z;
    const int tid = threadIdx.x;
    {
        int r = tid >> 3, dg = (tid & 7) << 2;   // r: c, dg: d
        *(float4*)&tile[r][dg] =
            *(const float4*)(Wo + ((size_t)q * CDD + c0 + r) * DIMM + d0 + dg);
    }
    __syncthreads();
    {
        int dd = tid >> 3, cg = (tid & 7) << 2;
        unsigned short h4[4], l4[4];
        #pragma unroll
        for (int u = 0; u < 4; u++) {
            float v = tile[cg + u][dd];
            h4[u] = f2bf(v);
            l4[u] = f2bf(v - bf2f(h4[u]));
        }
        size_t o = ((size_t)q * DIMM + d0 + dd) * CDD + c0 + cg;
        *(ushort4*)(Th + o) = *(ushort4*)h4;
        *(ushort4*)(Tl + o) = *(ushort4*)l4;
    }
}

// prep: E fp32 -> Eh/El bf16 [qk][c] + ||E||^2
__global__ __launch_bounds__(64) void prep_esplit(
    const float* __restrict__ E,
    unsigned short* __restrict__ Eh, unsigned short* __restrict__ El,
    float* __restrict__ en)
{
    int row = blockIdx.x, lane = threadIdx.x;
    const float* e = E + (size_t)row * CDD;
    float v0 = e[lane * 2], v1 = e[lane * 2 + 1];
    unsigned short h2[2], l2[2];
    h2[0] = f2bf(v0); l2[0] = f2bf(v0 - bf2f(h2[0]));
    h2[1] = f2bf(v1); l2[1] = f2bf(v1 - bf2f(h2[1]));
    size_t o = (size_t)row * CDD + lane * 2;
    *(ushort2*)(Eh + o) = *(ushort2*)h2;
    *(ushort2*)(El + o) = *(ushort2*)l2;
    float s = v0 * v0 + v1 * v1;
    #pragma unroll
    for (int off = 32; off > 0; off >>= 1) s += __shfl_down(s, off);
    if (lane == 0) en[row] = s;
}

// prep: prefix sums of b_out: Pb[q][d] = sum_{p<q} bo[p][d], q=0..8
__global__ __launch_bounds__(256) void prep_pb(const float* __restrict__ bo,
                                               float* __restrict__ Pb)
{
    int d = blockIdx.x * 256 + threadIdx.x;
    float s = 0.f;
    Pb[d] = 0.f;
    for (int q = 0; q < QQ; q++) {
        s += bo[(size_t)q * DIMM + d];
        Pb[(size_t)(q + 1) * DIMM + d] = s;
    }
}

// prep: cvec[q][c] = sum_d Pb[q][d] * Wi[q][d][c]
__global__ __launch_bounds__(128) void prep_cvec(const float* __restrict__ Pb,
                                                 const float* __restrict__ Wi,
                                                 float* __restrict__ cvec)
{
    int q = blockIdx.x, c = threadIdx.x;
    float s = 0.f;
    for (int d = 0; d < DIMM; d++)
        s = fmaf(Pb[(size_t)q * DIMM + d], Wi[((size_t)q * DIMM + d) * CDD + c], s);
    cvec[(size_t)q * CDD + c] = s;
}

// ===========================================================================
// hemb[q][m][c] via 6-pass 3-way split MFMA. A staged in LDS; B-frags loaded
// DIRECTLY from global (WiT is L2-resident) — no B staging, 30 KB LDS.
__global__ __launch_bounds__(256) void k_hemb6(
    const unsigned short* __restrict__ A0, const unsigned short* __restrict__ A1,
    const unsigned short* __restrict__ A2,
    const unsigned short* __restrict__ B0g, const unsigned short* __restrict__ B1g,
    const unsigned short* __restrict__ B2g,
    const float* __restrict__ biAll, float* __restrict__ hembAll)
{
    const int q = blockIdx.z;
    const unsigned short* Bq0 = B0g + (size_t)q * CDD * DIMM;
    const unsigned short* Bq1 = B1g + (size_t)q * CDD * DIMM;
    const unsigned short* Bq2 = B2g + (size_t)q * CDD * DIMM;
    const float* bias = biAll + (size_t)q * CDD;
    float* C = hembAll + (size_t)q * MM * CDD;

    __shared__ unsigned short sA[3][128 * 40];
    const int tid = threadIdx.x, lane = tid & 63, w = tid >> 6;
    const int wy = w >> 1, wx = w & 1;
    const int col = lane & 15, quad = lane >> 4;
    const int m0 = blockIdx.x * 128;

    f32x4 acc[4][4];
    #pragma unroll
    for (int i = 0; i < 4; i++)
        #pragma unroll
        for (int j = 0; j < 4; j++) acc[i][j] = (f32x4){0.f, 0.f, 0.f, 0.f};

    // staging map: r = tid&127 (row), s = (tid>>7)*16 (k-half) -> 2-way banks
    const int r = tid & 127, s = (tid >> 7) << 4;
    const int so = r * 40 + s;

    // B-frag row offsets (direct global), quad's k-octet baked in
    size_t boff[4];
    #pragma unroll
    for (int nt = 0; nt < 4; nt++)
        boff[nt] = (size_t)(wx * 64 + nt * 16 + col) * DIMM + quad * 8;

    for (int k0 = 0; k0 < DIMM; k0 += 32) {
        {
            size_t ga = (size_t)(m0 + r) * DIMM + k0 + s;
            *(bf16x8*)(sA[0] + so)     = *(const bf16x8*)(A0 + ga);
            *(bf16x8*)(sA[0] + so + 8) = *(const bf16x8*)(A0 + ga + 8);
            *(bf16x8*)(sA[1] + so)     = *(const bf16x8*)(A1 + ga);
            *(bf16x8*)(sA[1] + so + 8) = *(const bf16x8*)(A1 + ga + 8);
            *(bf16x8*)(sA[2] + so)     = *(const bf16x8*)(A2 + ga);
            *(bf16x8*)(sA[2] + so + 8) = *(const bf16x8*)(A2 + ga + 8);
        }
        __syncthreads();

        // direct-global B-frags for this k-chunk
        bf16x8 b0[4], b1[4], b2[4];
        #pragma unroll
        for (int nt = 0; nt < 4; nt++) {
            b0[nt] = *(const bf16x8*)(Bq0 + boff[nt] + k0);
            b1[nt] = *(const bf16x8*)(Bq1 + boff[nt] + k0);
            b2[nt] = *(const bf16x8*)(Bq2 + boff[nt] + k0);
        }
        #pragma unroll
        for (int mt = 0; mt < 4; mt++) {
            int rr = wy * 64 + mt * 16 + col;
            int o = rr * 40 + quad * 8;
            bf16x8 a0 = *(const bf16x8*)(sA[0] + o);
            bf16x8 a1 = *(const bf16x8*)(sA[1] + o);
            bf16x8 a2 = *(const bf16x8*)(sA[2] + o);
            #pragma unroll
            for (int nt = 0; nt < 4; nt++) {
                f32x4 a = acc[mt][nt];
                a = __builtin_amdgcn_mfma_f32_16x16x32_bf16(a0, b0[nt], a, 0, 0, 0);
                a = __builtin_amdgcn_mfma_f32_16x16x32_bf16(a1, b0[nt], a, 0, 0, 0);
                a = __builtin_amdgcn_mfma_f32_16x16x32_bf16(a2, b0[nt], a, 0, 0, 0);
                a = __builtin_amdgcn_mfma_f32_16x16x32_bf16(a0, b1[nt], a, 0, 0, 0);
                a = __builtin_amdgcn_mfma_f32_16x16x32_bf16(a1, b1[nt], a, 0, 0, 0);
                a = __builtin_amdgcn_mfma_f32_16x16x32_bf16(a0, b2[nt], a, 0, 0, 0);
                acc[mt][nt] = a;
            }
        }
        __syncthreads();
    }
    #pragma unroll
    for (int nt = 0; nt < 4; nt++) {
        int n = wx * 64 + nt * 16 + col;
        float bv = bias[n];
        #pragma unroll
        for (int mt = 0; mt < 4; mt++) {
            #pragma unroll
            for (int rr = 0; rr < 4; rr++) {
                int m = m0 + wy * 64 + mt * 16 + quad * 4 + rr;
                C[(size_t)m * CDD + n] = acc[mt][nt][rr] + bv;
            }
        }
    }
}

// ===========================================================================
// 3-pass core (for D = E·Wo). A: [m][k] hi/lo, B: [n][k] hi/lo, 128×128 tile.
__device__ __forceinline__ void gemm3p_core(
    const unsigned short* __restrict__ Ah, const unsigned short* __restrict__ Al,
    const unsigned short* __restrict__ Bh, const unsigned short* __restrict__ Bl,
    float* __restrict__ C, int ldc, const float* __restrict__ bias,
    int K, int m0, int n0)
{
    __shared__ unsigned short sAh[128 * 72], sAl[128 * 72];
    __shared__ unsigned short sBh[128 * 72], sBl[128 * 72];
    const int tid = threadIdx.x, lane = tid & 63, w = tid >> 6;
    const int wy = w >> 1, wx = w & 1;
    const int col = lane & 15, quad = lane >> 4;

    f32x4 acc[4][4];
    #pragma unroll
    for (int i = 0; i < 4; i++)
        #pragma unroll
        for (int j = 0; j < 4; j++) acc[i][j] = (f32x4){0.f, 0.f, 0.f, 0.f};

    for (int k0 = 0; k0 < K; k0 += 64) {
        int r = tid >> 1, s = (tid & 1) * 32;
        {
            const unsigned short* ga = Ah + (size_t)(m0 + r) * K + k0 + s;
            const unsigned short* gl = Al + (size_t)(m0 + r) * K + k0 + s;
            const unsigned short* gb = Bh + (size_t)(n0 + r) * K + k0 + s;
            const unsigned short* gc = Bl + (size_t)(n0 + r) * K + k0 + s;
            int o = r * 72 + s;
            #pragma unroll
            for (int u = 0; u < 4; u++) {
                *(bf16x8*)(sAh + o + u * 8) = *(const bf16x8*)(ga + u * 8);
                *(bf16x8*)(sAl + o + u * 8) = *(const bf16x8*)(gl + u * 8);
                *(bf16x8*)(sBh + o + u * 8) = *(const bf16x8*)(gb + u * 8);
                *(bf16x8*)(sBl + o + u * 8) = *(const bf16x8*)(gc + u * 8);
            }
        }
        __syncthreads();
        #pragma unroll
        for (int ks = 0; ks < 2; ks++) {
            bf16x8 ah[4], al[4], bh[4], bl[4];
            int oo = ((ks << 2) + quad) << 3;
            #pragma unroll
            for (int mt = 0; mt < 4; mt++) {
                int rr = wy * 64 + mt * 16 + col;
                ah[mt] = *(const bf16x8*)(sAh + rr * 72 + oo);
                al[mt] = *(const bf16x8*)(sAl + rr * 72 + oo);
            }
            #pragma unroll
            for (int nt = 0; nt < 4; nt++) {
                int rr = wx * 64 + nt * 16 + col;
                bh[nt] = *(const bf16x8*)(sBh + rr * 72 + oo);
                bl[nt] = *(const bf16x8*)(sBl + rr * 72 + oo);
            }
            #pragma unroll
            for (int mt = 0; mt < 4; mt++)
                #pragma unroll
                for (int nt = 0; nt < 4; nt++) {
                    f32x4 a = acc[mt][nt];
                    a = __builtin_amdgcn_mfma_f32_16x16x32_bf16(ah[mt], bh[nt], a, 0, 0, 0);
                    a = __builtin_amdgcn_mfma_f32_16x16x32_bf16(al[mt], bh[nt], a, 0, 0, 0);
                    a = __builtin_amdgcn_mfma_f32_16x16x32_bf16(ah[mt], bl[nt], a, 0, 0, 0);
                    acc[mt][nt] = a;
                }
        }
        __syncthreads();
    }
    #pragma unroll
    for (int nt = 0; nt < 4; nt++) {
        int n = n0 + wx * 64 + nt * 16 + col;
        float bv = bias ? bias[n - n0] : 0.f;
        #pragma unroll
        for (int mt = 0; mt < 4; mt++) {
            #pragma unroll
            for (int rr = 0; rr < 4; rr++) {
                int m = m0 + wy * 64 + mt * 16 + quad * 4 + rr;
                C[(size_t)m * ldc + n] = acc[mt][nt][rr] + bv;
            }
        }
    }
}

__global__ __launch_bounds__(256) void k_D(
    const unsigned short* __restrict__ Eh, const unsigned short* __restrict__ El,
    const unsigned short* __restrict__ WoTh, const unsigned short* __restrict__ WoTl,
    float* __restrict__ D)
{
    int p = blockIdx.z;
    gemm3p_core(Eh + (size_t)p * KK * CDD, El + (size_t)p * KK * CDD,
                WoTh + (size_t)p * DIMM * CDD, WoTl + (size_t)p * DIMM * CDD,
                D + (size_t)p * KK * DIMM, DIMM, nullptr,
                CDD, blockIdx.x * 128, blockIdx.y * 128);
}

// ===========================================================================
// small fp32 GEMM (64×64 tile): C = A[M×K]·B[K×N]
__device__ __forceinline__ void f32gemm64(
    const float* __restrict__ A, int lda, const float* __restrict__ B, int ldb,
    float* __restrict__ C, int ldc, int K, int m0, int n0)
{
    __shared__ float As[32][68];
    __shared__ float Bs[32][68];
    const int tid = threadIdx.x, tx = tid & 15, ty = tid >> 4;
    float dot[4][4];
    #pragma unroll
    for (int i = 0; i < 4; i++)
        #pragma unroll
        for (int j = 0; j < 4; j++) dot[i][j] = 0.f;

    for (int k0 = 0; k0 < K; k0 += 32) {
        #pragma unroll
        for (int i = 0; i < 2; i++) {
            int j = i * 256 + tid;
            int r = j >> 3, kc = (j & 7) << 2;
            float4 a = *(const float4*)(A + (size_t)(m0 + r) * lda + k0 + kc);
            As[kc + 0][r] = a.x; As[kc + 1][r] = a.y;
            As[kc + 2][r] = a.z; As[kc + 3][r] = a.w;
        }
        #pragma unroll
        for (int i = 0; i < 2; i++) {
            int j = i * 256 + tid;
            int kr = j >> 4, nc = (j & 15) << 2;
            *(float4*)&Bs[kr][nc] = *(const float4*)(B + (size_t)(k0 + kr) * ldb + n0 + nc);
        }
        __syncthreads();
        #pragma unroll 4
        for (int kk = 0; kk < 32; kk++) {
            float4 a4 = *(float4*)&As[kk][ty << 2];
            float4 b4 = *(float4*)&Bs[kk][tx << 2];
            float av[4] = {a4.x, a4.y, a4.z, a4.w};
            float bv[4] = {b4.x, b4.y, b4.z, b4.w};
            #pragma unroll
            for (int i = 0; i < 4; i++)
                #pragma unroll
                for (int j = 0; j < 4; j++)
                    dot[i][j] = fmaf(av[i], bv[j], dot[i][j]);
        }
        __syncthreads();
    }
    #pragma unroll
    for (int i = 0; i < 4; i++)
        *(float4*)(C + (size_t)(m0 + (ty << 2) + i) * ldc + n0 + (tx << 2)) =
            *(float4*)&dot[i][0];
}

// G[pair] = Wo_p · Wi_q   (128×128, K=1024)
__global__ __launch_bounds__(256) void gemm_G(
    const float* __restrict__ Wo, const float* __restrict__ Wi, float* __restrict__ G)
{
    int z = blockIdx.z, p = z, q = 1;
    while (p >= q) { p -= q; q++; }
    f32gemm64(Wo + (size_t)p * CDD * DIMM, DIMM,
              Wi + (size_t)q * DIMM * CDD, CDD,
              G + (size_t)z * CDD * CDD, CDD, DIMM,
              blockIdx.y * 64, blockIdx.x * 64);
}

// F[pair] = E_p · G[pair]   (1024×128, K=128)
__global__ __launch_bounds__(256) void gemm_F(
    const float* __restrict__ E, const float* __restrict__ G, float* __restrict__ F)
{
    int z = blockIdx.z, p = z, q = 1;
    while (p >= q) { p -= q; q++; }
    f32gemm64(E + (size_t)p * KK * CDD, CDD,
              G + (size_t)z * CDD * CDD, CDD,
              F + (size_t)z * KK * CDD, CDD, CDD,
              blockIdx.y * 64, blockIdx.x * 64);
}

// ===========================================================================
__device__ __forceinline__ void top4_insert(float (&v)[4], int (&id)[4],
                                            float nv, int nid) {
    if (nv < v[3] || (nv == v[3] && nid < id[3])) {
        v[3] = nv; id[3] = nid;
        #pragma unroll
        for (int p = 3; p > 0; p--) {
            if (v[p] < v[p - 1] || (v[p] == v[p - 1] && id[p] < id[p - 1])) {
                float tv = v[p]; v[p] = v[p - 1]; v[p - 1] = tv;
                int ti = id[p]; id[p] = id[p - 1]; id[p - 1] = ti;
            } else break;
        }
    }
}

// Chain: h = hemb_q - cvec_q - sum_{p<q} F[p][idx_p], then argmin via 3-pass
// MFMA with B-frags DIRECT FROM GLOBAL (no E staging, no k-loop barriers),
// top2/lane + exact fp32 rescore of merged top-4. 32 tokens/block.
__global__ __launch_bounds__(256) void chain_pa(
    const float* __restrict__ hemb_q, const float* __restrict__ Fq,
    const float* __restrict__ cvec_q, const int* __restrict__ idx_all, int q,
    const unsigned short* __restrict__ EhT_q, const unsigned short* __restrict__ ElT_q,
    const float* __restrict__ Ef_q, const float* __restrict__ en_q,
    int* __restrict__ idx_out)
{
    __shared__ __align__(16) char smem[49664];
    float* Hs    = (float*)smem;                 // [32][132] fp32
    float* candv = (float*)(smem + 16896);       // [32][128]
    int*   candi = (int*)(smem + 16896 + 16384); // [32][128]

    const int tid = threadIdx.x;
    const int m0 = blockIdx.x * 32;
    const int lane = tid & 63, w = tid >> 6;
    const int col = lane & 15, quad = lane >> 4;

    // ---- gather h ----
    {
        int t = tid >> 3, cg = (tid & 7) << 4;
        float hv[16];
        const float* hp = hemb_q + (size_t)(m0 + t) * CDD + cg;
        #pragma unroll
        for (int u = 0; u < 4; u++) *(float4*)&hv[u * 4] = *(const float4*)(hp + u * 4);
        const float* cv = cvec_q + cg;
        #pragma unroll
        for (int u = 0; u < 16; u++) hv[u] -= cv[u];
        for (int p = 0; p < q; p++) {
            int k = idx_all[(size_t)p * MM + m0 + t];
            const float* fp = Fq + ((size_t)p * KK + k) * CDD + cg;
            #pragma unroll
            for (int u = 0; u < 4; u++) {
                float4 f4 = *(const float4*)(fp + u * 4);
                hv[u * 4 + 0] -= f4.x; hv[u * 4 + 1] -= f4.y;
                hv[u * 4 + 2] -= f4.z; hv[u * 4 + 3] -= f4.w;
            }
        }
        float* hd = Hs + t * 132 + cg;
        #pragma unroll
        for (int u = 0; u < 4; u++) *(float4*)(hd + u * 4) = *(float4*)&hv[u * 4];
    }
    __syncthreads();

    // ---- A-frags (h) hi/lo in regs ----
    bf16x8 ah[2][4], al[2][4];
    #pragma unroll
    for (int m = 0; m < 2; m++) {
        int t = m * 16 + col;
        #pragma unroll
        for (int ks = 0; ks < 4; ks++) {
            const float* hp = Hs + t * 132 + ks * 32 + quad * 8;
            float v[8];
            *(f32x4*)(v) = *(const f32x4*)(hp);
            *(f32x4*)(v + 4) = *(const f32x4*)(hp + 4);
            short hs[8], ls[8];
            #pragma unroll
            for (int u = 0; u < 8; u++) {
                unsigned short u1 = f2bf(v[u]);
                hs[u] = (short)u1;
                ls[u] = (short)f2bf(v[u] - bf2f(u1));
            }
            ah[m][ks] = (bf16x8){hs[0],hs[1],hs[2],hs[3],hs[4],hs[5],hs[6],hs[7]};
            al[m][ks] = (bf16x8){ls[0],ls[1],ls[2],ls[3],ls[4],ls[5],ls[6],ls[7]};
        }
    }

    float tv1[8], tv2[8]; int ti1[8], ti2[8];
    #pragma unroll
    for (int s = 0; s < 8; s++) { tv1[s] = INFINITY; tv2[s] = INFINITY;
                                  ti1[s] = 1 << 30; ti2[s] = 1 << 30; }
    const int lc = (w << 4) + col;   // this lane's code within 64-chunk

    for (int k0 = 0; k0 < KK; k0 += 64) {
        // B-frags direct from global (L2-resident codebook)
        bf16x8 bh[4], bl[4];
        const unsigned short* gh = EhT_q + (size_t)(k0 + lc) * CDD;
        const unsigned short* gl = ElT_q + (size_t)(k0 + lc) * CDD;
        #pragma unroll
        for (int ks = 0; ks < 4; ks++) {
            int o = (((ks << 2) + quad) << 3);
            bh[ks] = *(const bf16x8*)(gh + o);
            bl[ks] = *(const bf16x8*)(gl + o);
        }
        f32x4 d2[2];
        #pragma unroll
        for (int m = 0; m < 2; m++) {
            f32x4 dd = (f32x4){0.f, 0.f, 0.f, 0.f};
            #pragma unroll
            for (int ks = 0; ks < 4; ks++) {
                dd = __builtin_amdgcn_mfma_f32_16x16x32_bf16(ah[m][ks], bh[ks], dd, 0, 0, 0);
                dd = __builtin_amdgcn_mfma_f32_16x16x32_bf16(al[m][ks], bh[ks], dd, 0, 0, 0);
                dd = __builtin_amdgcn_mfma_f32_16x16x32_bf16(ah[m][ks], bl[ks], dd, 0, 0, 0);
            }
            d2[m] = dd;
        }
        int kcode = k0 + lc;
        float env = en_q[kcode];
        #pragma unroll
        for (int m = 0; m < 2; m++)
            #pragma unroll
            for (int rr = 0; rr < 4; rr++) {
                float dist = fmaf(-2.f, d2[m][rr], env);
                int s = (m << 2) + rr;
                if (dist < tv1[s]) { tv2[s] = tv1[s]; ti2[s] = ti1[s];
                                     tv1[s] = dist;   ti1[s] = kcode; }
                else if (dist < tv2[s]) { tv2[s] = dist; ti2[s] = kcode; }
            }
    }

    // ---- dump per-lane top2 ----
    #pragma unroll
    for (int m = 0; m < 2; m++)
        #pragma unroll
        for (int rr = 0; rr < 4; rr++) {
            int t = m * 16 + (quad << 2) + rr;
            int s = (m << 2) + rr;
            int base = t * 128 + lc * 2;
            candv[base] = tv1[s];     candi[base] = ti1[s];
            candv[base + 1] = tv2[s]; candi[base + 1] = ti2[s];
        }
    __syncthreads();

    // ---- merge to top-4 (8 threads per token) + exact fp32 rescore ----
    {
        int t = tid >> 3, j = tid & 7;
        float v[4]; int id[4];
        #pragma unroll
        for (int p = 0; p < 4; p++) { v[p] = INFINITY; id[p] = 1 << 30; }
        #pragma unroll
        for (int e = 0; e < 16; e++)
            top4_insert(v, id, candv[t * 128 + j * 16 + e], candi[t * 128 + j * 16 + e]);
        #pragma unroll
        for (int d = 1; d < 8; d <<= 1) {
            #pragma unroll
            for (int s = 0; s < 4; s++) {
                float pv = __shfl_xor(v[s], d);
                int   pi = __shfl_xor(id[s], d);
                top4_insert(v, id, pv, pi);
            }
        }
        // rescore: thread j handles candidate j&3, half j>>2
        int cand = id[j & 3];
        const float* er = Ef_q + (size_t)cand * CDD + ((j >> 2) << 6);
        const float* hr = Hs + t * 132 + ((j >> 2) << 6);
        float dot = 0.f;
        #pragma unroll 8
        for (int c = 0; c < 64; c++) dot = fmaf(hr[c], er[c], dot);
        dot += __shfl_xor(dot, 4);
        float dist = fmaf(-2.f, dot, en_q[cand]);
        #pragma unroll
        for (int d = 1; d < 4; d <<= 1) {
            float ov = __shfl_xor(dist, d);
            int   oi = __shfl_xor(cand, d);
            if (ov < dist || (ov == dist && oi < cand)) { dist = ov; cand = oi; }
        }
        if (j == 0) idx_out[m0 + t] = cand;
    }
}

// ===========================================================================
// out[b][d][t] = sum_p D_p[idx_p[m]][d] + Pb[8][d]
__global__ __launch_bounds__(256) void final_out(
    const int* __restrict__ idx_all, const float* __restrict__ D,
    const float* __restrict__ PbFull, float* __restrict__ out)
{
    __shared__ int ids[QQ][64];
    const int tid = threadIdx.x;
    const int m0 = blockIdx.x * 64, d0 = blockIdx.y * 64;
    const int b = m0 / TT, t0 = m0 % TT;
    const int tx = tid & 15, ty = tid >> 4;
    #pragma unroll
    for (int e = 0; e < 2; e++) {
        int j = e * 256 + tid;
        int p = j >> 6, tt = j & 63;
        ids[p][tt] = idx_all[(size_t)p * MM + m0 + tt];
    }
    __syncthreads();

    float s[4][4];
    #pragma unroll
    for (int j = 0; j < 4; j++) {
        float bs = PbFull[d0 + (ty << 2) + j];
        #pragma unroll
        for (int i = 0; i < 4; i++) s[i][j] = bs;
    }
    #pragma unroll
    for (int p = 0; p < QQ; p++) {
        #pragma unroll
        for (int i = 0; i < 4; i++) {
            int row = ids[p][tx + (i << 4)];
            float4 dv = *(const float4*)(D + ((size_t)p * KK + row) * DIMM + d0 + (ty << 2));
            s[i][0] += dv.x; s[i][1] += dv.y; s[i][2] += dv.z; s[i][3] += dv.w;
        }
    }
    #pragma unroll
    for (int j = 0; j < 4; j++) {
        float* base = out + (size_t)b * DIMM * TT + (size_t)(d0 + (ty << 2) + j) * TT + t0 + tx;
        #pragma unroll
        for (int i = 0; i < 4; i++) base[i << 4] = s[i][j];
    }
}

// ===========================================================================
extern "C" void kernel_launch(void* const* d_in, const int* in_sizes, int n_in,
                              void* d_out, int out_size, void* d_ws, size_t ws_size,
                              hipStream_t stream) {
    const float* emb   = (const float*)d_in[0];
    const float* W_in  = (const float*)d_in[1];
    const float* b_in  = (const float*)d_in[2];
    const float* W_out = (const float*)d_in[3];
    const float* b_out = (const float*)d_in[4];
    const float* embed = (const float*)d_in[5];
    float* out = (float*)d_out;

    char* ws = (char*)d_ws;
    size_t off = 0;
    auto alloc = [&](size_t bytes) { char* p = ws + off; off = (off + bytes + 255) & ~(size_t)255; return p; };
    int*   idxbuf = (int*)alloc((size_t)QQ * MM * 4);
    float* en     = (float*)alloc((size_t)QQ * KK * 4);
    unsigned short* EhT = (unsigned short*)alloc((size_t)QQ * KK * CDD * 2);
    unsigned short* ElT = (unsigned short*)alloc((size_t)QQ * KK * CDD * 2);
    unsigned short* WiTh = (unsigned short*)alloc((size_t)QQ * CDD * DIMM * 2);
    unsigned short* WiTm = (unsigned short*)alloc((size_t)QQ * CDD * DIMM * 2);
    unsigned short* WiTl = (unsigned short*)alloc((size_t)QQ * CDD * DIMM * 2);
    unsigned short* WoTh = (unsigned short*)alloc((size_t)QQ * DIMM * CDD * 2);
    unsigned short* WoTl = (unsigned short*)alloc((size_t)QQ * DIMM * CDD * 2);
    unsigned short* embTh = (unsigned short*)alloc((size_t)MM * DIMM * 2);
    unsigned short* embTm = (unsigned short*)alloc((size_t)MM * DIMM * 2);
    unsigned short* embTl = (unsigned short*)alloc((size_t)MM * DIMM * 2);
    float* hemb = (float*)alloc((size_t)QQ * MM * CDD * 4);
    float* G    = (float*)alloc((size_t)NPAIR * CDD * CDD * 4);
    float* F    = (float*)alloc((size_t)NPAIR * KK * CDD * 4);
    float* D    = (float*)alloc((size_t)QQ * KK * DIMM * 4);
    float* Pb   = (float*)alloc((size_t)(QQ + 1) * DIMM * 4);
    float* cvec = (float*)alloc((size_t)QQ * CDD * 4);

    // preps (parallel, off-chain)
    prep_embT<<<dim3(TT / 32, DIMM / 32, BB), 256, 0, stream>>>(emb, embTh, embTm, embTl);
    prep_wiT<<<dim3(DIMM / 32, CDD / 32, QQ), 256, 0, stream>>>(W_in, WiTh, WiTm, WiTl);
    prep_woT<<<dim3(CDD / 32, DIMM / 32, QQ), 256, 0, stream>>>(W_out, WoTh, WoTl);
    prep_esplit<<<QQ * KK, 64, 0, stream>>>(embed, EhT, ElT, en);
    prep_pb<<<DIMM / 256, 256, 0, stream>>>(b_out, Pb);
    prep_cvec<<<QQ, 128, 0, stream>>>(Pb, W_in, cvec);

    k_hemb6<<<dim3(MM / 128, 1, QQ), 256, 0, stream>>>(
        embTh, embTm, embTl, WiTh, WiTm, WiTl, b_in, hemb);
    gemm_G<<<dim3(2, 2, NPAIR), 256, 0, stream>>>(W_out, W_in, G);
    gemm_F<<<dim3(2, 16, NPAIR), 256, 0, stream>>>(embed, G, F);
    k_D<<<dim3(KK / 128, DIMM / 128, QQ), 256, 0, stream>>>(EhT, ElT, WoTh, WoTl, D);

    // sequential chain: only gather + argmin
    for (int q = 0; q < QQ; q++) {
        chain_pa<<<MM / 32, 256, 0, stream>>>(
            hemb + (size_t)q * MM * CDD,
            F + (size_t)(q * (q - 1) / 2) * KK * CDD,
            cvec + (size_t)q * CDD,
            idxbuf, q,
            EhT + (size_t)q * KK * CDD, ElT + (size_t)q * KK * CDD,
            embed + (size_t)q * KK * CDD, en + (size_t)q * KK,
            idxbuf + (size_t)q * MM);
    }
    final_out<<<dim3(MM / 64, DIMM / 64), 256, 0, stream>>>(idxbuf, D, Pb + (size_t)QQ * DIMM, out);
}

// Round 7
// 842.033 us; speedup vs baseline: 1.1766x; 1.1766x over previous
//
#include <hip/hip_runtime.h>
#include <hip/hip_bf16.h>
#include <math.h>

#define BB   8
#define DIMM 1024
#define TT   2048
#define CDD  128
#define KK   1024
#define QQ   8
#define MM   (BB*TT)     // 16384 tokens
#define NPAIR 28         // q*(q-1)/2 pairs p<q

typedef __attribute__((ext_vector_type(8))) short bf16x8;
typedef __attribute__((ext_vector_type(8))) _Float16 f16x8;
typedef __attribute__((ext_vector_type(4))) _Float16 f16x4;
typedef __attribute__((ext_vector_type(4))) float f32x4;

static __device__ __forceinline__ unsigned short f2bf(float f) {
    __hip_bfloat16 h = __float2bfloat16(f);
    unsigned short u; __builtin_memcpy(&u, &h, 2); return u;
}
static __device__ __forceinline__ float bf2f(unsigned short u) {
    __hip_bfloat16 h; __builtin_memcpy(&h, &u, 2); return __bfloat162float(h);
}

// ===========================================================================
// prep: emb [b][d][t] fp32 -> embT fp16 hi/lo [m=b*T+t][d], scaled x256
__global__ __launch_bounds__(256) void prep_embT16(
    const float* __restrict__ emb,
    _Float16* __restrict__ Th, _Float16* __restrict__ Tl)
{
    __shared__ float tile[32][36];
    const int t0 = blockIdx.x * 32, d0 = blockIdx.y * 32, b = blockIdx.z;
    const int tid = threadIdx.x;
    {
        int r = tid >> 3, cg = (tid & 7) << 2;
        *(float4*)&tile[r][cg] =
            *(const float4*)(emb + ((size_t)b * DIMM + d0 + r) * TT + t0 + cg);
    }
    __syncthreads();
    {
        int tt = tid >> 3, dg = (tid & 7) << 2;
        f16x4 h4, l4;
        #pragma unroll
        for (int u = 0; u < 4; u++) {
            float v = tile[dg + u][tt] * 256.0f;
            _Float16 hh = (_Float16)v;
            _Float16 ll = (_Float16)(v - (float)hh);
            h4[u] = hh; l4[u] = ll;
        }
        size_t o = ((size_t)b * TT + t0 + tt) * DIMM + d0 + dg;
        *(f16x4*)(Th + o) = h4;
        *(f16x4*)(Tl + o) = l4;
    }
}

// prep: Wi [q][d][c] -> WiT fp16 hi/lo [q][c][d], scaled x1024
__global__ __launch_bounds__(256) void prep_wiT16(
    const float* __restrict__ Wi,
    _Float16* __restrict__ Th, _Float16* __restrict__ Tl)
{
    __shared__ float tile[32][36];
    const int d0 = blockIdx.x * 32, c0 = blockIdx.y * 32, q = blockIdx.z;
    const int tid = threadIdx.x;
    {
        int r = tid >> 3, cg = (tid & 7) << 2;   // r: d, cg: c
        *(float4*)&tile[r][cg] =
            *(const float4*)(Wi + ((size_t)q * DIMM + d0 + r) * CDD + c0 + cg);
    }
    __syncthreads();
    {
        int cc = tid >> 3, dg = (tid & 7) << 2;
        f16x4 h4, l4;
        #pragma unroll
        for (int u = 0; u < 4; u++) {
            float v = tile[dg + u][cc] * 1024.0f;
            _Float16 hh = (_Float16)v;
            _Float16 ll = (_Float16)(v - (float)hh);
            h4[u] = hh; l4[u] = ll;
        }
        size_t o = ((size_t)q * CDD + c0 + cc) * DIMM + d0 + dg;
        *(f16x4*)(Th + o) = h4;
        *(f16x4*)(Tl + o) = l4;
    }
}

// prep: Wo [q][c][d] -> WoT bf16 hi/lo [q][d][c]
__global__ __launch_bounds__(256) void prep_woT(
    const float* __restrict__ Wo,
    unsigned short* __restrict__ Th, unsigned short* __restrict__ Tl)
{
    __shared__ float tile[32][36];
    const int c0 = blockIdx.x * 32, d0 = blockIdx.y * 32, q = blockIdx.z;
    const int tid = threadIdx.x;
    {
        int r = tid >> 3, dg = (tid & 7) << 2;   // r: c, dg: d
        *(float4*)&tile[r][dg] =
            *(const float4*)(Wo + ((size_t)q * CDD + c0 + r) * DIMM + d0 + dg);
    }
    __syncthreads();
    {
        int dd = tid >> 3, cg = (tid & 7) << 2;
        unsigned short h4[4], l4[4];
        #pragma unroll
        for (int u = 0; u < 4; u++) {
            float v = tile[cg + u][dd];
            h4[u] = f2bf(v);
            l4[u] = f2bf(v - bf2f(h4[u]));
        }
        size_t o = ((size_t)q * DIMM + d0 + dd) * CDD + c0 + cg;
        *(ushort4*)(Th + o) = *(ushort4*)h4;
        *(ushort4*)(Tl + o) = *(ushort4*)l4;
    }
}

// prep: E fp32 -> Eh/El bf16 [qk][c] + ||E||^2
__global__ __launch_bounds__(64) void prep_esplit(
    const float* __restrict__ E,
    unsigned short* __restrict__ Eh, unsigned short* __restrict__ El,
    float* __restrict__ en)
{
    int row = blockIdx.x, lane = threadIdx.x;
    const float* e = E + (size_t)row * CDD;
    float v0 = e[lane * 2], v1 = e[lane * 2 + 1];
    unsigned short h2[2], l2[2];
    h2[0] = f2bf(v0); l2[0] = f2bf(v0 - bf2f(h2[0]));
    h2[1] = f2bf(v1); l2[1] = f2bf(v1 - bf2f(h2[1]));
    size_t o = (size_t)row * CDD + lane * 2;
    *(ushort2*)(Eh + o) = *(ushort2*)h2;
    *(ushort2*)(El + o) = *(ushort2*)l2;
    float s = v0 * v0 + v1 * v1;
    #pragma unroll
    for (int off = 32; off > 0; off >>= 1) s += __shfl_down(s, off);
    if (lane == 0) en[row] = s;
}

// prep: prefix sums of b_out: Pb[q][d] = sum_{p<q} bo[p][d], q=0..8
__global__ __launch_bounds__(256) void prep_pb(const float* __restrict__ bo,
                                               float* __restrict__ Pb)
{
    int d = blockIdx.x * 256 + threadIdx.x;
    float s = 0.f;
    Pb[d] = 0.f;
    for (int q = 0; q < QQ; q++) {
        s += bo[(size_t)q * DIMM + d];
        Pb[(size_t)(q + 1) * DIMM + d] = s;
    }
}

// prep: cvec[q][c] = sum_d Pb[q][d] * Wi[q][d][c]
__global__ __launch_bounds__(128) void prep_cvec(const float* __restrict__ Pb,
                                                 const float* __restrict__ Wi,
                                                 float* __restrict__ cvec)
{
    int q = blockIdx.x, c = threadIdx.x;
    float s = 0.f;
    for (int d = 0; d < DIMM; d++)
        s = fmaf(Pb[(size_t)q * DIMM + d], Wi[((size_t)q * DIMM + d) * CDD + c], s);
    cvec[(size_t)q * CDD + c] = s;
}

// ===========================================================================
// hemb[q][m][c] via 4-pass fp16 2-way-split MFMA (fp32-grade: 2^-24 input rep,
// all 4 products kept). Inputs pre-scaled (emb x256, Wi x1024) to dodge fp16
// subnormals; epilogue descales by exact 2^-18. LDS: 4 arrays x 10 KB, BK=32.
__global__ __launch_bounds__(256) void k_hemb4(
    const _Float16* __restrict__ A0, const _Float16* __restrict__ A1,
    const _Float16* __restrict__ B0g, const _Float16* __restrict__ B1g,
    const float* __restrict__ biAll, float* __restrict__ hembAll)
{
    const int q = blockIdx.z;
    const _Float16* Bq0 = B0g + (size_t)q * CDD * DIMM;
    const _Float16* Bq1 = B1g + (size_t)q * CDD * DIMM;
    const float* bias = biAll + (size_t)q * CDD;
    float* C = hembAll + (size_t)q * MM * CDD;

    __shared__ __align__(16) _Float16 sA[2][128 * 40];
    __shared__ __align__(16) _Float16 sB[2][128 * 40];
    const int tid = threadIdx.x, lane = tid & 63, w = tid >> 6;
    const int wy = w >> 1, wx = w & 1;
    const int col = lane & 15, quad = lane >> 4;
    const int m0 = blockIdx.x * 128;

    f32x4 acc[4][4];
    #pragma unroll
    for (int i = 0; i < 4; i++)
        #pragma unroll
        for (int j = 0; j < 4; j++) acc[i][j] = (f32x4){0.f, 0.f, 0.f, 0.f};

    const int r = tid >> 1, s = (tid & 1) << 4;   // row, k-half (16 halfs)
    const int so = r * 40 + s;

    for (int k0 = 0; k0 < DIMM; k0 += 32) {
        {
            size_t ga = (size_t)(m0 + r) * DIMM + k0 + s;
            size_t gb = (size_t)r * DIMM + k0 + s;
            *(f16x8*)(sA[0] + so)     = *(const f16x8*)(A0 + ga);
            *(f16x8*)(sA[0] + so + 8) = *(const f16x8*)(A0 + ga + 8);
            *(f16x8*)(sA[1] + so)     = *(const f16x8*)(A1 + ga);
            *(f16x8*)(sA[1] + so + 8) = *(const f16x8*)(A1 + ga + 8);
            *(f16x8*)(sB[0] + so)     = *(const f16x8*)(Bq0 + gb);
            *(f16x8*)(sB[0] + so + 8) = *(const f16x8*)(Bq0 + gb + 8);
            *(f16x8*)(sB[1] + so)     = *(const f16x8*)(Bq1 + gb);
            *(f16x8*)(sB[1] + so + 8) = *(const f16x8*)(Bq1 + gb + 8);
        }
        __syncthreads();

        f16x8 b0[4], b1[4];
        #pragma unroll
        for (int nt = 0; nt < 4; nt++) {
            int rr = wx * 64 + nt * 16 + col;
            int o = rr * 40 + quad * 8;
            b0[nt] = *(const f16x8*)(sB[0] + o);
            b1[nt] = *(const f16x8*)(sB[1] + o);
        }
        #pragma unroll
        for (int mt = 0; mt < 4; mt++) {
            int rr = wy * 64 + mt * 16 + col;
            int o = rr * 40 + quad * 8;
            f16x8 a0 = *(const f16x8*)(sA[0] + o);
            f16x8 a1 = *(const f16x8*)(sA[1] + o);
            #pragma unroll
            for (int nt = 0; nt < 4; nt++) {
                f32x4 a = acc[mt][nt];
                a = __builtin_amdgcn_mfma_f32_16x16x32_f16(a0, b0[nt], a, 0, 0, 0);
                a = __builtin_amdgcn_mfma_f32_16x16x32_f16(a1, b0[nt], a, 0, 0, 0);
                a = __builtin_amdgcn_mfma_f32_16x16x32_f16(a0, b1[nt], a, 0, 0, 0);
                a = __builtin_amdgcn_mfma_f32_16x16x32_f16(a1, b1[nt], a, 0, 0, 0);
                acc[mt][nt] = a;
            }
        }
        __syncthreads();
    }
    const float inv = 1.0f / 262144.0f;   // 2^-18: emb x256 * Wi x1024
    #pragma unroll
    for (int nt = 0; nt < 4; nt++) {
        int n = wx * 64 + nt * 16 + col;
        float bv = bias[n];
        #pragma unroll
        for (int mt = 0; mt < 4; mt++) {
            #pragma unroll
            for (int rr = 0; rr < 4; rr++) {
                int m = m0 + wy * 64 + mt * 16 + quad * 4 + rr;
                C[(size_t)m * CDD + n] = fmaf(acc[mt][nt][rr], inv, bv);
            }
        }
    }
}

// ===========================================================================
// 3-pass bf16 core (for D = E·Wo). A: [m][k] hi/lo, B: [n][k] hi/lo.
__device__ __forceinline__ void gemm3p_core(
    const unsigned short* __restrict__ Ah, const unsigned short* __restrict__ Al,
    const unsigned short* __restrict__ Bh, const unsigned short* __restrict__ Bl,
    float* __restrict__ C, int ldc, const float* __restrict__ bias,
    int K, int m0, int n0)
{
    __shared__ unsigned short sAh[128 * 72], sAl[128 * 72];
    __shared__ unsigned short sBh[128 * 72], sBl[128 * 72];
    const int tid = threadIdx.x, lane = tid & 63, w = tid >> 6;
    const int wy = w >> 1, wx = w & 1;
    const int col = lane & 15, quad = lane >> 4;

    f32x4 acc[4][4];
    #pragma unroll
    for (int i = 0; i < 4; i++)
        #pragma unroll
        for (int j = 0; j < 4; j++) acc[i][j] = (f32x4){0.f, 0.f, 0.f, 0.f};

    for (int k0 = 0; k0 < K; k0 += 64) {
        int r = tid >> 1, s = (tid & 1) * 32;
        {
            const unsigned short* ga = Ah + (size_t)(m0 + r) * K + k0 + s;
            const unsigned short* gl = Al + (size_t)(m0 + r) * K + k0 + s;
            const unsigned short* gb = Bh + (size_t)(n0 + r) * K + k0 + s;
            const unsigned short* gc = Bl + (size_t)(n0 + r) * K + k0 + s;
            int o = r * 72 + s;
            #pragma unroll
            for (int u = 0; u < 4; u++) {
                *(bf16x8*)(sAh + o + u * 8) = *(const bf16x8*)(ga + u * 8);
                *(bf16x8*)(sAl + o + u * 8) = *(const bf16x8*)(gl + u * 8);
                *(bf16x8*)(sBh + o + u * 8) = *(const bf16x8*)(gb + u * 8);
                *(bf16x8*)(sBl + o + u * 8) = *(const bf16x8*)(gc + u * 8);
            }
        }
        __syncthreads();
        #pragma unroll
        for (int ks = 0; ks < 2; ks++) {
            bf16x8 ah[4], al[4], bh[4], bl[4];
            int oo = ((ks << 2) + quad) << 3;
            #pragma unroll
            for (int mt = 0; mt < 4; mt++) {
                int rr = wy * 64 + mt * 16 + col;
                ah[mt] = *(const bf16x8*)(sAh + rr * 72 + oo);
                al[mt] = *(const bf16x8*)(sAl + rr * 72 + oo);
            }
            #pragma unroll
            for (int nt = 0; nt < 4; nt++) {
                int rr = wx * 64 + nt * 16 + col;
                bh[nt] = *(const bf16x8*)(sBh + rr * 72 + oo);
                bl[nt] = *(const bf16x8*)(sBl + rr * 72 + oo);
            }
            #pragma unroll
            for (int mt = 0; mt < 4; mt++)
                #pragma unroll
                for (int nt = 0; nt < 4; nt++) {
                    f32x4 a = acc[mt][nt];
                    a = __builtin_amdgcn_mfma_f32_16x16x32_bf16(ah[mt], bh[nt], a, 0, 0, 0);
                    a = __builtin_amdgcn_mfma_f32_16x16x32_bf16(al[mt], bh[nt], a, 0, 0, 0);
                    a = __builtin_amdgcn_mfma_f32_16x16x32_bf16(ah[mt], bl[nt], a, 0, 0, 0);
                    acc[mt][nt] = a;
                }
        }
        __syncthreads();
    }
    #pragma unroll
    for (int nt = 0; nt < 4; nt++) {
        int n = n0 + wx * 64 + nt * 16 + col;
        float bv = bias ? bias[n - n0] : 0.f;
        #pragma unroll
        for (int mt = 0; mt < 4; mt++) {
            #pragma unroll
            for (int rr = 0; rr < 4; rr++) {
                int m = m0 + wy * 64 + mt * 16 + quad * 4 + rr;
                C[(size_t)m * ldc + n] = acc[mt][nt][rr] + bv;
            }
        }
    }
}

__global__ __launch_bounds__(256) void k_D(
    const unsigned short* __restrict__ Eh, const unsigned short* __restrict__ El,
    const unsigned short* __restrict__ WoTh, const unsigned short* __restrict__ WoTl,
    float* __restrict__ D)
{
    int p = blockIdx.z;
    gemm3p_core(Eh + (size_t)p * KK * CDD, El + (size_t)p * KK * CDD,
                WoTh + (size_t)p * DIMM * CDD, WoTl + (size_t)p * DIMM * CDD,
                D + (size_t)p * KK * DIMM, DIMM, nullptr,
                CDD, blockIdx.x * 128, blockIdx.y * 128);
}

// ===========================================================================
// small fp32 GEMM (64×64 tile): C = A[M×K]·B[K×N]
__device__ __forceinline__ void f32gemm64(
    const float* __restrict__ A, int lda, const float* __restrict__ B, int ldb,
    float* __restrict__ C, int ldc, int K, int m0, int n0)
{
    __shared__ float As[32][68];
    __shared__ float Bs[32][68];
    const int tid = threadIdx.x, tx = tid & 15, ty = tid >> 4;
    float dot[4][4];
    #pragma unroll
    for (int i = 0; i < 4; i++)
        #pragma unroll
        for (int j = 0; j < 4; j++) dot[i][j] = 0.f;

    for (int k0 = 0; k0 < K; k0 += 32) {
        #pragma unroll
        for (int i = 0; i < 2; i++) {
            int j = i * 256 + tid;
            int r = j >> 3, kc = (j & 7) << 2;
            float4 a = *(const float4*)(A + (size_t)(m0 + r) * lda + k0 + kc);
            As[kc + 0][r] = a.x; As[kc + 1][r] = a.y;
            As[kc + 2][r] = a.z; As[kc + 3][r] = a.w;
        }
        #pragma unroll
        for (int i = 0; i < 2; i++) {
            int j = i * 256 + tid;
            int kr = j >> 4, nc = (j & 15) << 2;
            *(float4*)&Bs[kr][nc] = *(const float4*)(B + (size_t)(k0 + kr) * ldb + n0 + nc);
        }
        __syncthreads();
        #pragma unroll 4
        for (int kk = 0; kk < 32; kk++) {
            float4 a4 = *(float4*)&As[kk][ty << 2];
            float4 b4 = *(float4*)&Bs[kk][tx << 2];
            float av[4] = {a4.x, a4.y, a4.z, a4.w};
            float bv[4] = {b4.x, b4.y, b4.z, b4.w};
            #pragma unroll
            for (int i = 0; i < 4; i++)
                #pragma unroll
                for (int j = 0; j < 4; j++)
                    dot[i][j] = fmaf(av[i], bv[j], dot[i][j]);
        }
        __syncthreads();
    }
    #pragma unroll
    for (int i = 0; i < 4; i++)
        *(float4*)(C + (size_t)(m0 + (ty << 2) + i) * ldc + n0 + (tx << 2)) =
            *(float4*)&dot[i][0];
}

// G[pair] = Wo_p · Wi_q   (128×128, K=1024)
__global__ __launch_bounds__(256) void gemm_G(
    const float* __restrict__ Wo, const float* __restrict__ Wi, float* __restrict__ G)
{
    int z = blockIdx.z, p = z, q = 1;
    while (p >= q) { p -= q; q++; }
    f32gemm64(Wo + (size_t)p * CDD * DIMM, DIMM,
              Wi + (size_t)q * DIMM * CDD, CDD,
              G + (size_t)z * CDD * CDD, CDD, DIMM,
              blockIdx.y * 64, blockIdx.x * 64);
}

// F[pair] = E_p · G[pair]   (1024×128, K=128)
__global__ __launch_bounds__(256) void gemm_F(
    const float* __restrict__ E, const float* __restrict__ G, float* __restrict__ F)
{
    int z = blockIdx.z, p = z, q = 1;
    while (p >= q) { p -= q; q++; }
    f32gemm64(E + (size_t)p * KK * CDD, CDD,
              G + (size_t)z * CDD * CDD, CDD,
              F + (size_t)z * KK * CDD, CDD, CDD,
              blockIdx.y * 64, blockIdx.x * 64);
}

// ===========================================================================
__device__ __forceinline__ void top4_insert(float (&v)[4], int (&id)[4],
                                            float nv, int nid) {
    if (nv < v[3] || (nv == v[3] && nid < id[3])) {
        v[3] = nv; id[3] = nid;
        #pragma unroll
        for (int p = 3; p > 0; p--) {
            if (v[p] < v[p - 1] || (v[p] == v[p - 1] && id[p] < id[p - 1])) {
                float tv = v[p]; v[p] = v[p - 1]; v[p - 1] = tv;
                int ti = id[p]; id[p] = id[p - 1]; id[p - 1] = ti;
            } else break;
        }
    }
}

// Chain: h = hemb_q - cvec_q - sum_{p<q} F[p][idx_p], then argmin via 3-pass
// MFMA with B-frags direct from global (row-contiguous, L2-resident),
// top2/lane + exact fp32 rescore of merged top-4. 32 tokens/block.
__global__ __launch_bounds__(256) void chain_pa(
    const float* __restrict__ hemb_q, const float* __restrict__ Fq,
    const float* __restrict__ cvec_q, const int* __restrict__ idx_all, int q,
    const unsigned short* __restrict__ EhT_q, const unsigned short* __restrict__ ElT_q,
    const float* __restrict__ Ef_q, const float* __restrict__ en_q,
    int* __restrict__ idx_out)
{
    __shared__ __align__(16) char smem[49664];
    float* Hs    = (float*)smem;                 // [32][132] fp32
    float* candv = (float*)(smem + 16896);       // [32][128]
    int*   candi = (int*)(smem + 16896 + 16384); // [32][128]

    const int tid = threadIdx.x;
    const int m0 = blockIdx.x * 32;
    const int lane = tid & 63, w = tid >> 6;
    const int col = lane & 15, quad = lane >> 4;

    // ---- gather h ----
    {
        int t = tid >> 3, cg = (tid & 7) << 4;
        float hv[16];
        const float* hp = hemb_q + (size_t)(m0 + t) * CDD + cg;
        #pragma unroll
        for (int u = 0; u < 4; u++) *(float4*)&hv[u * 4] = *(const float4*)(hp + u * 4);
        const float* cv = cvec_q + cg;
        #pragma unroll
        for (int u = 0; u < 16; u++) hv[u] -= cv[u];
        for (int p = 0; p < q; p++) {
            int k = idx_all[(size_t)p * MM + m0 + t];
            const float* fp = Fq + ((size_t)p * KK + k) * CDD + cg;
            #pragma unroll
            for (int u = 0; u < 4; u++) {
                float4 f4 = *(const float4*)(fp + u * 4);
                hv[u * 4 + 0] -= f4.x; hv[u * 4 + 1] -= f4.y;
                hv[u * 4 + 2] -= f4.z; hv[u * 4 + 3] -= f4.w;
            }
        }
        float* hd = Hs + t * 132 + cg;
        #pragma unroll
        for (int u = 0; u < 4; u++) *(float4*)(hd + u * 4) = *(float4*)&hv[u * 4];
    }
    __syncthreads();

    // ---- A-frags (h) hi/lo in regs ----
    bf16x8 ah[2][4], al[2][4];
    #pragma unroll
    for (int m = 0; m < 2; m++) {
        int t = m * 16 + col;
        #pragma unroll
        for (int ks = 0; ks < 4; ks++) {
            const float* hp = Hs + t * 132 + ks * 32 + quad * 8;
            float v[8];
            *(f32x4*)(v) = *(const f32x4*)(hp);
            *(f32x4*)(v + 4) = *(const f32x4*)(hp + 4);
            short hs[8], ls[8];
            #pragma unroll
            for (int u = 0; u < 8; u++) {
                unsigned short u1 = f2bf(v[u]);
                hs[u] = (short)u1;
                ls[u] = (short)f2bf(v[u] - bf2f(u1));
            }
            ah[m][ks] = (bf16x8){hs[0],hs[1],hs[2],hs[3],hs[4],hs[5],hs[6],hs[7]};
            al[m][ks] = (bf16x8){ls[0],ls[1],ls[2],ls[3],ls[4],ls[5],ls[6],ls[7]};
        }
    }

    float tv1[8], tv2[8]; int ti1[8], ti2[8];
    #pragma unroll
    for (int s = 0; s < 8; s++) { tv1[s] = INFINITY; tv2[s] = INFINITY;
                                  ti1[s] = 1 << 30; ti2[s] = 1 << 30; }
    const int lc = (w << 4) + col;   // this lane's code within 64-chunk

    for (int k0 = 0; k0 < KK; k0 += 64) {
        bf16x8 bh[4], bl[4];
        const unsigned short* gh = EhT_q + (size_t)(k0 + lc) * CDD;
        const unsigned short* gl = ElT_q + (size_t)(k0 + lc) * CDD;
        #pragma unroll
        for (int ks = 0; ks < 4; ks++) {
            int o = (((ks << 2) + quad) << 3);
            bh[ks] = *(const bf16x8*)(gh + o);
            bl[ks] = *(const bf16x8*)(gl + o);
        }
        f32x4 d2[2];
        #pragma unroll
        for (int m = 0; m < 2; m++) {
            f32x4 dd = (f32x4){0.f, 0.f, 0.f, 0.f};
            #pragma unroll
            for (int ks = 0; ks < 4; ks++) {
                dd = __builtin_amdgcn_mfma_f32_16x16x32_bf16(ah[m][ks], bh[ks], dd, 0, 0, 0);
                dd = __builtin_amdgcn_mfma_f32_16x16x32_bf16(al[m][ks], bh[ks], dd, 0, 0, 0);
                dd = __builtin_amdgcn_mfma_f32_16x16x32_bf16(ah[m][ks], bl[ks], dd, 0, 0, 0);
            }
            d2[m] = dd;
        }
        int kcode = k0 + lc;
        float env = en_q[kcode];
        #pragma unroll
        for (int m = 0; m < 2; m++)
            #pragma unroll
            for (int rr = 0; rr < 4; rr++) {
                float dist = fmaf(-2.f, d2[m][rr], env);
                int s = (m << 2) + rr;
                if (dist < tv1[s]) { tv2[s] = tv1[s]; ti2[s] = ti1[s];
                                     tv1[s] = dist;   ti1[s] = kcode; }
                else if (dist < tv2[s]) { tv2[s] = dist; ti2[s] = kcode; }
            }
    }

    // ---- dump per-lane top2 ----
    #pragma unroll
    for (int m = 0; m < 2; m++)
        #pragma unroll
        for (int rr = 0; rr < 4; rr++) {
            int t = m * 16 + (quad << 2) + rr;
            int s = (m << 2) + rr;
            int base = t * 128 + lc * 2;
            candv[base] = tv1[s];     candi[base] = ti1[s];
            candv[base + 1] = tv2[s]; candi[base + 1] = ti2[s];
        }
    __syncthreads();

    // ---- merge to top-4 (8 threads per token) + exact fp32 rescore ----
    {
        int t = tid >> 3, j = tid & 7;
        float v[4]; int id[4];
        #pragma unroll
        for (int p = 0; p < 4; p++) { v[p] = INFINITY; id[p] = 1 << 30; }
        #pragma unroll
        for (int e = 0; e < 16; e++)
            top4_insert(v, id, candv[t * 128 + j * 16 + e], candi[t * 128 + j * 16 + e]);
        #pragma unroll
        for (int d = 1; d < 8; d <<= 1) {
            #pragma unroll
            for (int s = 0; s < 4; s++) {
                float pv = __shfl_xor(v[s], d);
                int   pi = __shfl_xor(id[s], d);
                top4_insert(v, id, pv, pi);
            }
        }
        int cand = id[j & 3];
        const float* er = Ef_q + (size_t)cand * CDD + ((j >> 2) << 6);
        const float* hr = Hs + t * 132 + ((j >> 2) << 6);
        float dot = 0.f;
        #pragma unroll 8
        for (int c = 0; c < 64; c++) dot = fmaf(hr[c], er[c], dot);
        dot += __shfl_xor(dot, 4);
        float dist = fmaf(-2.f, dot, en_q[cand]);
        #pragma unroll
        for (int d = 1; d < 4; d <<= 1) {
            float ov = __shfl_xor(dist, d);
            int   oi = __shfl_xor(cand, d);
            if (ov < dist || (ov == dist && oi < cand)) { dist = ov; cand = oi; }
        }
        if (j == 0) idx_out[m0 + t] = cand;
    }
}

// ===========================================================================
// out[b][d][t] = sum_p D_p[idx_p[m]][d] + Pb[8][d]
__global__ __launch_bounds__(256) void final_out(
    const int* __restrict__ idx_all, const float* __restrict__ D,
    const float* __restrict__ PbFull, float* __restrict__ out)
{
    __shared__ int ids[QQ][64];
    const int tid = threadIdx.x;
    const int m0 = blockIdx.x * 64, d0 = blockIdx.y * 64;
    const int b = m0 / TT, t0 = m0 % TT;
    const int tx = tid & 15, ty = tid >> 4;
    #pragma unroll
    for (int e = 0; e < 2; e++) {
        int j = e * 256 + tid;
        int p = j >> 6, tt = j & 63;
        ids[p][tt] = idx_all[(size_t)p * MM + m0 + tt];
    }
    __syncthreads();

    float s[4][4];
    #pragma unroll
    for (int j = 0; j < 4; j++) {
        float bs = PbFull[d0 + (ty << 2) + j];
        #pragma unroll
        for (int i = 0; i < 4; i++) s[i][j] = bs;
    }
    #pragma unroll
    for (int p = 0; p < QQ; p++) {
        #pragma unroll
        for (int i = 0; i < 4; i++) {
            int row = ids[p][tx + (i << 4)];
            float4 dv = *(const float4*)(D + ((size_t)p * KK + row) * DIMM + d0 + (ty << 2));
            s[i][0] += dv.x; s[i][1] += dv.y; s[i][2] += dv.z; s[i][3] += dv.w;
        }
    }
    #pragma unroll
    for (int j = 0; j < 4; j++) {
        float* base = out + (size_t)b * DIMM * TT + (size_t)(d0 + (ty << 2) + j) * TT + t0 + tx;
        #pragma unroll
        for (int i = 0; i < 4; i++) base[i << 4] = s[i][j];
    }
}

// ===========================================================================
extern "C" void kernel_launch(void* const* d_in, const int* in_sizes, int n_in,
                              void* d_out, int out_size, void* d_ws, size_t ws_size,
                              hipStream_t stream) {
    const float* emb   = (const float*)d_in[0];
    const float* W_in  = (const float*)d_in[1];
    const float* b_in  = (const float*)d_in[2];
    const float* W_out = (const float*)d_in[3];
    const float* b_out = (const float*)d_in[4];
    const float* embed = (const float*)d_in[5];
    float* out = (float*)d_out;

    char* ws = (char*)d_ws;
    size_t off = 0;
    auto alloc = [&](size_t bytes) { char* p = ws + off; off = (off + bytes + 255) & ~(size_t)255; return p; };
    int*   idxbuf = (int*)alloc((size_t)QQ * MM * 4);
    float* en     = (float*)alloc((size_t)QQ * KK * 4);
    unsigned short* EhT = (unsigned short*)alloc((size_t)QQ * KK * CDD * 2);
    unsigned short* ElT = (unsigned short*)alloc((size_t)QQ * KK * CDD * 2);
    unsigned short* WoTh = (unsigned short*)alloc((size_t)QQ * DIMM * CDD * 2);
    unsigned short* WoTl = (unsigned short*)alloc((size_t)QQ * DIMM * CDD * 2);
    _Float16* wiFh = (_Float16*)alloc((size_t)QQ * CDD * DIMM * 2);
    _Float16* wiFl = (_Float16*)alloc((size_t)QQ * CDD * DIMM * 2);
    _Float16* embFh = (_Float16*)alloc((size_t)MM * DIMM * 2);
    _Float16* embFl = (_Float16*)alloc((size_t)MM * DIMM * 2);
    float* hemb = (float*)alloc((size_t)QQ * MM * CDD * 4);
    float* G    = (float*)alloc((size_t)NPAIR * CDD * CDD * 4);
    float* F    = (float*)alloc((size_t)NPAIR * KK * CDD * 4);
    float* D    = (float*)alloc((size_t)QQ * KK * DIMM * 4);
    float* Pb   = (float*)alloc((size_t)(QQ + 1) * DIMM * 4);
    float* cvec = (float*)alloc((size_t)QQ * CDD * 4);

    // preps (parallel, off-chain)
    prep_embT16<<<dim3(TT / 32, DIMM / 32, BB), 256, 0, stream>>>(emb, embFh, embFl);
    prep_wiT16<<<dim3(DIMM / 32, CDD / 32, QQ), 256, 0, stream>>>(W_in, wiFh, wiFl);
    prep_woT<<<dim3(CDD / 32, DIMM / 32, QQ), 256, 0, stream>>>(W_out, WoTh, WoTl);
    prep_esplit<<<QQ * KK, 64, 0, stream>>>(embed, EhT, ElT, en);
    prep_pb<<<DIMM / 256, 256, 0, stream>>>(b_out, Pb);
    prep_cvec<<<QQ, 128, 0, stream>>>(Pb, W_in, cvec);

    k_hemb4<<<dim3(MM / 128, 1, QQ), 256, 0, stream>>>(
        embFh, embFl, wiFh, wiFl, b_in, hemb);
    gemm_G<<<dim3(2, 2, NPAIR), 256, 0, stream>>>(W_out, W_in, G);
    gemm_F<<<dim3(2, 16, NPAIR), 256, 0, stream>>>(embed, G, F);
    k_D<<<dim3(KK / 128, DIMM / 128, QQ), 256, 0, stream>>>(EhT, ElT, WoTh, WoTl, D);

    // sequential chain: only gather + argmin
    for (int q = 0; q < QQ; q++) {
        chain_pa<<<MM / 32, 256, 0, stream>>>(
            hemb + (size_t)q * MM * CDD,
            F + (size_t)(q * (q - 1) / 2) * KK * CDD,
            cvec + (size_t)q * CDD,
            idxbuf, q,
            EhT + (size_t)q * KK * CDD, ElT + (size_t)q * KK * CDD,
            embed + (size_t)q * KK * CDD, en + (size_t)q * KK,
            idxbuf + (size_t)q * MM);
    }
    final_out<<<dim3(MM / 64, DIMM / 64), 256, 0, stream>>>(idxbuf, D, Pb + (size_t)QQ * DIMM, out);
}